// Round 9
// baseline (1268.895 us; speedup 1.0000x reference)
//
#include <hip/hip_runtime.h>

#define N_NODES 100000
#define N_EDGES 1280000
#define HID 64
#define N_ETYPE 8

// ---- workspace byte offsets (all 128B-aligned) ----
#define WS_HT    0ull            // Htn[n][512] f32 = 204,800,000 B
#define WS_MAGG  204800000ull    // N*64 f32   =  25,600,000 B
#define WS_OFFS  230400000ull    // N i32
#define WS_DEG   230800000ull    // N i32
#define WS_CUR   231200000ull    // N i32
#define WS_CSR   231600000ull    // E i32 = 5,120,000 B
#define WS_BSUM  236720000ull    // 128 i32
#define WS_BOFF  236720512ull    // 128 i32
// total ~236.8 MB

__device__ __forceinline__ int ufl(int x) { return __builtin_amdgcn_readfirstlane(x); }

// ---------------------------------------------------------------------------
// K1 v5: lane = node. h-row in 64 VGPRs (compile-time indexed); A rows are
// WAVE-UNIFORM scalar loads (readfirstlane offset -> s_load), consumed as the
// SGPR operand of v_fma. No LDS, no broadcast ds_reads (v4 was LDS-issue
// bound: 96+ ds_read_b128/node). Out: per-lane float4 stores, 256B/node/t.
// ---------------------------------------------------------------------------
#define K1DOT(mm, oo)                                                         \
    {                                                                         \
        const float* w_ = em + ufl(t * 4096 + (m4 * 4 + (mm)) * 64);          \
        float a0 = 0.f, a1 = 0.f, a2 = 0.f, a3 = 0.f;                         \
        _Pragma("unroll")                                                     \
        for (int hh = 0; hh < 64; hh += 4) {                                  \
            a0 = fmaf(w_[hh + 0], xh[hh + 0], a0);                            \
            a1 = fmaf(w_[hh + 1], xh[hh + 1], a1);                            \
            a2 = fmaf(w_[hh + 2], xh[hh + 2], a2);                            \
            a3 = fmaf(w_[hh + 3], xh[hh + 3], a3);                            \
        }                                                                     \
        oo = (a0 + a1) + (a2 + a3);                                           \
    }

__global__ __launch_bounds__(256, 2) void k1_ht(const float* __restrict__ h,
                                                const float* __restrict__ em,
                                                float* __restrict__ Htn) {
    int n = blockIdx.x * 256 + threadIdx.x;
    int nc = n < N_NODES ? n : N_NODES - 1;
    bool valid = n < N_NODES;

    float xh[64];
    {
        const float4* hr = (const float4*)(h + (size_t)nc * HID);
        #pragma unroll
        for (int q = 0; q < 16; ++q) {
            float4 v = hr[q];
            xh[4*q+0] = v.x; xh[4*q+1] = v.y; xh[4*q+2] = v.z; xh[4*q+3] = v.w;
        }
    }

    float* orow = Htn + (size_t)nc * 512;
    #pragma unroll 1
    for (int t = 0; t < N_ETYPE; ++t) {
        #pragma unroll 1
        for (int m4 = 0; m4 < 16; ++m4) {
            float o0, o1, o2, o3;
            K1DOT(0, o0)
            K1DOT(1, o1)
            K1DOT(2, o2)
            K1DOT(3, o3)
            if (valid) {
                float4 o4; o4.x = o0; o4.y = o1; o4.z = o2; o4.w = o3;
                *(float4*)(orow + t * 64 + m4 * 4) = o4;
            }
        }
    }
}

// ---------------------------------------------------------------------------
// CSR build: histogram -> 2-level exclusive scan -> fill
// ---------------------------------------------------------------------------
__global__ void k_hist(const int* __restrict__ dst, int* __restrict__ deg) {
    int e = blockIdx.x * blockDim.x + threadIdx.x;
    if (e < N_EDGES) atomicAdd(&deg[dst[e]], 1);
}

__global__ void k_scan_a(const int* __restrict__ deg, int* __restrict__ offs,
                         int* __restrict__ bsum) {
    __shared__ int sh[256];
    int tid  = threadIdx.x;
    int base = blockIdx.x * 1024 + tid * 4;
    int d0 = (base + 0 < N_NODES) ? deg[base + 0] : 0;
    int d1 = (base + 1 < N_NODES) ? deg[base + 1] : 0;
    int d2 = (base + 2 < N_NODES) ? deg[base + 2] : 0;
    int d3 = (base + 3 < N_NODES) ? deg[base + 3] : 0;
    int s = d0 + d1 + d2 + d3;
    sh[tid] = s;
    __syncthreads();
    for (int ofs = 1; ofs < 256; ofs <<= 1) {
        int v = (tid >= ofs) ? sh[tid - ofs] : 0;
        __syncthreads();
        sh[tid] += v;
        __syncthreads();
    }
    int excl = sh[tid] - s;
    if (base + 0 < N_NODES) offs[base + 0] = excl;
    if (base + 1 < N_NODES) offs[base + 1] = excl + d0;
    if (base + 2 < N_NODES) offs[base + 2] = excl + d0 + d1;
    if (base + 3 < N_NODES) offs[base + 3] = excl + d0 + d1 + d2;
    if (tid == 255) bsum[blockIdx.x] = sh[255];
}

__global__ void k_scan_b(const int* __restrict__ bsum, int* __restrict__ boff) {
    __shared__ int sh[128];
    int tid = threadIdx.x;                 // 128 threads, NB = 98
    int v = (tid < 98) ? bsum[tid] : 0;
    sh[tid] = v;
    __syncthreads();
    for (int ofs = 1; ofs < 128; ofs <<= 1) {
        int u = (tid >= ofs) ? sh[tid - ofs] : 0;
        __syncthreads();
        sh[tid] += u;
        __syncthreads();
    }
    if (tid < 98) boff[tid] = sh[tid] - v;
}

__global__ void k_scan_c(int* __restrict__ offs, const int* __restrict__ boff,
                         int* __restrict__ cur) {
    int tid  = threadIdx.x;
    int add  = boff[blockIdx.x];
    int base = blockIdx.x * 1024 + tid * 4;
    #pragma unroll
    for (int q = 0; q < 4; ++q) {
        int i = base + q;
        if (i < N_NODES) { int v = offs[i] + add; offs[i] = v; cur[i] = v; }
    }
}

__global__ void k_fill(const int* __restrict__ src, const int* __restrict__ dst,
                       const int* __restrict__ typ, int* __restrict__ cur,
                       int* __restrict__ csr) {
    int e = blockIdx.x * blockDim.x + threadIdx.x;
    if (e < N_EDGES) {
        int d = dst[e];
        int p = atomicAdd(&cur[d], 1);
        csr[p] = (src[e] << 3) | typ[e];    // (src*8 + t) -> row of Htn[n][512]
    }
}

// ---------------------------------------------------------------------------
// K4: m_agg[d][m] = sum over in-edges of Htn[src*8+t][m]; wave per node.
// 4-deep unroll for memory-level parallelism on the random 256B gathers.
// ---------------------------------------------------------------------------
__global__ void k_agg(const float* __restrict__ Htn, const int* __restrict__ offs,
                      const int* __restrict__ deg, const int* __restrict__ csr,
                      float* __restrict__ magg) {
    int gwave = (int)((blockIdx.x * blockDim.x + threadIdx.x) >> 6);
    int lane  = threadIdx.x & 63;
    int d = __builtin_amdgcn_readfirstlane(gwave);
    if (d >= N_NODES) return;
    int off = offs[d];
    int cnt = deg[d];
    float acc0 = 0.f, acc1 = 0.f, acc2 = 0.f, acc3 = 0.f;
    int k = 0;
    for (; k + 3 < cnt; k += 4) {
        int i0 = csr[off + k + 0];
        int i1 = csr[off + k + 1];
        int i2 = csr[off + k + 2];
        int i3 = csr[off + k + 3];
        acc0 += Htn[(size_t)i0 * 64 + lane];
        acc1 += Htn[(size_t)i1 * 64 + lane];
        acc2 += Htn[(size_t)i2 * 64 + lane];
        acc3 += Htn[(size_t)i3 * 64 + lane];
    }
    for (; k < cnt; ++k) acc0 += Htn[(size_t)csr[off + k] * 64 + lane];
    magg[(size_t)d * HID + lane] = (acc0 + acc1) + (acc2 + acc3);
}

// ---------------------------------------------------------------------------
// K5 v4: fused GRU, lane = node. magg row + h row in 128 VGPRs; the 6 weight
// rows per output m are wave-uniform s_loads. No LDS, no cross-wave exchange.
// h[n][m4] reloaded per m4 (L1-hot) to keep register indices compile-time.
// ---------------------------------------------------------------------------
#define GRUGATE(mm, oo, hvv)                                                  \
    {                                                                         \
        int m_ = m4 * 4 + (mm);                                               \
        const float* wir = w_ih + ufl(m_ * 64);                               \
        const float* wiz = w_ih + ufl((64 + m_) * 64);                        \
        const float* win = w_ih + ufl((128 + m_) * 64);                       \
        const float* whr = w_hh + ufl(m_ * 64);                               \
        const float* whz = w_hh + ufl((64 + m_) * 64);                        \
        const float* whn = w_hh + ufl((128 + m_) * 64);                       \
        float air = 0.f, aiz = 0.f, ain = 0.f;                                \
        float ahr = 0.f, ahz = 0.f, ahn = 0.f;                                \
        _Pragma("unroll")                                                     \
        for (int hh = 0; hh < 64; ++hh) {                                     \
            air = fmaf(wir[hh], xm[hh], air);                                 \
            aiz = fmaf(wiz[hh], xm[hh], aiz);                                 \
            ain = fmaf(win[hh], xm[hh], ain);                                 \
            ahr = fmaf(whr[hh], xh[hh], ahr);                                 \
            ahz = fmaf(whz[hh], xh[hh], ahz);                                 \
            ahn = fmaf(whn[hh], xh[hh], ahn);                                 \
        }                                                                     \
        float rr = air + b_ih[ufl(m_)] + ahr + b_hh[ufl(m_)];                 \
        float zz = aiz + b_ih[ufl(64 + m_)] + ahz + b_hh[ufl(64 + m_)];       \
        float inn = ain + b_ih[ufl(128 + m_)];                                \
        float hnn = ahn + b_hh[ufl(128 + m_)];                                \
        float r_ = 1.f / (1.f + __expf(-rr));                                 \
        float z_ = 1.f / (1.f + __expf(-zz));                                 \
        float n_ = tanhf(inn + r_ * hnn);                                     \
        oo = (1.f - z_) * n_ + z_ * (hvv);                                    \
    }

__global__ __launch_bounds__(256, 2) void k_gru(
        const float* __restrict__ h, const float* __restrict__ magg,
        const float* __restrict__ w_ih, const float* __restrict__ w_hh,
        const float* __restrict__ b_ih, const float* __restrict__ b_hh,
        float* __restrict__ out) {
    int n = blockIdx.x * 256 + threadIdx.x;
    int nc = n < N_NODES ? n : N_NODES - 1;
    bool valid = n < N_NODES;

    float xm[64], xh[64];
    {
        const float4* mr = (const float4*)(magg + (size_t)nc * HID);
        const float4* hr = (const float4*)(h + (size_t)nc * HID);
        #pragma unroll
        for (int q = 0; q < 16; ++q) {
            float4 a = mr[q];
            xm[4*q+0] = a.x; xm[4*q+1] = a.y; xm[4*q+2] = a.z; xm[4*q+3] = a.w;
            float4 b = hr[q];
            xh[4*q+0] = b.x; xh[4*q+1] = b.y; xh[4*q+2] = b.z; xh[4*q+3] = b.w;
        }
    }

    #pragma unroll 1
    for (int m4 = 0; m4 < 16; ++m4) {
        float4 hv = ((const float4*)(h + (size_t)nc * HID))[m4];
        float o0, o1, o2, o3;
        GRUGATE(0, o0, hv.x)
        GRUGATE(1, o1, hv.y)
        GRUGATE(2, o2, hv.z)
        GRUGATE(3, o3, hv.w)
        if (valid) {
            float4 o4; o4.x = o0; o4.y = o1; o4.z = o2; o4.w = o3;
            *(float4*)(out + (size_t)nc * HID + m4 * 4) = o4;
        }
    }
}

// ---------------------------------------------------------------------------
extern "C" void kernel_launch(void* const* d_in, const int* in_sizes, int n_in,
                              void* d_out, int out_size, void* d_ws, size_t ws_size,
                              hipStream_t stream) {
    const float* h    = (const float*)d_in[0];
    const float* em   = (const float*)d_in[1];
    const float* w_ih = (const float*)d_in[2];
    const float* w_hh = (const float*)d_in[3];
    const float* b_ih = (const float*)d_in[4];
    const float* b_hh = (const float*)d_in[5];
    const int* e_src  = (const int*)d_in[6];
    const int* e_dst  = (const int*)d_in[7];
    const int* e_typ  = (const int*)d_in[8];
    float* out = (float*)d_out;

    char* ws = (char*)d_ws;
    float* Htn  = (float*)(ws + WS_HT);
    float* magg = (float*)(ws + WS_MAGG);
    int* offs = (int*)(ws + WS_OFFS);
    int* deg  = (int*)(ws + WS_DEG);
    int* cur  = (int*)(ws + WS_CUR);
    int* csr  = (int*)(ws + WS_CSR);
    int* bsum = (int*)(ws + WS_BSUM);
    int* boff = (int*)(ws + WS_BOFF);

    hipMemsetAsync(deg, 0, (size_t)N_NODES * sizeof(int), stream);

    // Ht GEMM: 391 blocks x 256 lanes (lane = node)
    k1_ht<<<391, 256, 0, stream>>>(h, em, Htn);

    // CSR build
    k_hist<<<N_EDGES / 256, 256, 0, stream>>>(e_dst, deg);
    k_scan_a<<<98, 256, 0, stream>>>(deg, offs, bsum);
    k_scan_b<<<1, 128, 0, stream>>>(bsum, boff);
    k_scan_c<<<98, 256, 0, stream>>>(offs, boff, cur);
    k_fill<<<N_EDGES / 256, 256, 0, stream>>>(e_src, e_dst, e_typ, cur, csr);

    // aggregate: 100000 waves, 4 waves/block
    k_agg<<<25000, 256, 0, stream>>>(Htn, offs, deg, csr, magg);

    // fused GRU: 391 blocks x 256 lanes (lane = node)
    k_gru<<<391, 256, 0, stream>>>(h, magg, w_ih, w_hh, b_ih, b_hh, out);
}

// Round 10
// 487.766 us; speedup vs baseline: 2.6014x; 2.6014x over previous
//
#include <hip/hip_runtime.h>

#define N_NODES 100000
#define N_EDGES 1280000
#define HID 64
#define N_ETYPE 8

// ---- workspace byte offsets (all 128B-aligned) ----
#define WS_HT    0ull            // Htn[n][512] f32 = 204,800,000 B
#define WS_MAGG  204800000ull    // N*64 f32   =  25,600,000 B
#define WS_OFFS  230400000ull    // N i32
#define WS_DEG   230800000ull    // N i32
#define WS_CUR   231200000ull    // N i32
#define WS_CSR   231600000ull    // E i32 = 5,120,000 B
#define WS_BSUM  236720000ull    // 128 i32
#define WS_BOFF  236720512ull    // 128 i32
// total ~236.8 MB

// ---------------------------------------------------------------------------
// K1 v6: block-tiled f32 GEMM. C[n][c] = sum_k h[n][k]*em[c*64+k]
// (em IS B^T: c=t*64+m -> em[t*4096+m*64+k] = em[c*64+k]).
// Block = 64 nodes x 256 cols (blockIdx.y picks col half), K=64.
// As[k][i] transposed h-tile staged once; Bs[k][j] per 64-col chunk.
// Thread = 4 nodes x 4 cols; inner k: 2 ds_read_b128 + 16 FMA.
// Stores: lanes 0-15 write one 256B row segment -> full sectors, no
// write amplification (v5 measured 4.6x on scattered 16B/lane stores).
// ---------------------------------------------------------------------------
__global__ __launch_bounds__(256) void k1_ht(const float* __restrict__ h,
                                             const float* __restrict__ em,
                                             float* __restrict__ Htn) {
    __shared__ float As[64][64];
    __shared__ float Bs[64][64];
    int tid = threadIdx.x;
    int n0  = blockIdx.x * 64;
    const float4* h4  = (const float4*)h;
    const float4* em4 = (const float4*)em;

    // stage As[k][i] = h[n0+i][k], coalesced float4 reads, transposed writes
    #pragma unroll
    for (int p = 0; p < 4; ++p) {
        int idx = p * 256 + tid;
        int i = idx & 63, q = idx >> 6;          // q in 0..15
        int row = n0 + i; if (row >= N_NODES) row = N_NODES - 1;
        float4 v = h4[(size_t)row * 16 + q];
        As[q*4+0][i] = v.x; As[q*4+1][i] = v.y;
        As[q*4+2][i] = v.z; As[q*4+3][i] = v.w;
    }

    int i0 = (tid >> 4) * 4;     // node group
    int j0 = (tid & 15) * 4;     // col group

    #pragma unroll 1
    for (int cc = 0; cc < 4; ++cc) {
        int c0 = (blockIdx.y * 4 + cc) * 64;
        __syncthreads();   // previous compute done (and As ready on cc=0)
        #pragma unroll
        for (int p = 0; p < 4; ++p) {
            int idx = p * 256 + tid;
            int j = idx & 63, q = idx >> 6;
            float4 v = em4[(size_t)(c0 + j) * 16 + q];
            Bs[q*4+0][j] = v.x; Bs[q*4+1][j] = v.y;
            Bs[q*4+2][j] = v.z; Bs[q*4+3][j] = v.w;
        }
        __syncthreads();

        float acc[4][4];
        #pragma unroll
        for (int a = 0; a < 4; ++a)
            #pragma unroll
            for (int b = 0; b < 4; ++b) acc[a][b] = 0.f;

        #pragma unroll 16
        for (int k = 0; k < 64; ++k) {
            float4 av = *(const float4*)&As[k][i0];
            float4 bv = *(const float4*)&Bs[k][j0];
            acc[0][0] = fmaf(av.x, bv.x, acc[0][0]);
            acc[0][1] = fmaf(av.x, bv.y, acc[0][1]);
            acc[0][2] = fmaf(av.x, bv.z, acc[0][2]);
            acc[0][3] = fmaf(av.x, bv.w, acc[0][3]);
            acc[1][0] = fmaf(av.y, bv.x, acc[1][0]);
            acc[1][1] = fmaf(av.y, bv.y, acc[1][1]);
            acc[1][2] = fmaf(av.y, bv.z, acc[1][2]);
            acc[1][3] = fmaf(av.y, bv.w, acc[1][3]);
            acc[2][0] = fmaf(av.z, bv.x, acc[2][0]);
            acc[2][1] = fmaf(av.z, bv.y, acc[2][1]);
            acc[2][2] = fmaf(av.z, bv.z, acc[2][2]);
            acc[2][3] = fmaf(av.z, bv.w, acc[2][3]);
            acc[3][0] = fmaf(av.w, bv.x, acc[3][0]);
            acc[3][1] = fmaf(av.w, bv.y, acc[3][1]);
            acc[3][2] = fmaf(av.w, bv.z, acc[3][2]);
            acc[3][3] = fmaf(av.w, bv.w, acc[3][3]);
        }

        #pragma unroll
        for (int ni = 0; ni < 4; ++ni) {
            int row = n0 + i0 + ni;
            if (row < N_NODES) {
                float4 o; o.x = acc[ni][0]; o.y = acc[ni][1];
                o.z = acc[ni][2]; o.w = acc[ni][3];
                *(float4*)&Htn[(size_t)row * 512 + c0 + j0] = o;
            }
        }
    }
}

// ---------------------------------------------------------------------------
// CSR build: histogram -> 2-level exclusive scan -> fill
// ---------------------------------------------------------------------------
__global__ void k_hist(const int* __restrict__ dst, int* __restrict__ deg) {
    int e = blockIdx.x * blockDim.x + threadIdx.x;
    if (e < N_EDGES) atomicAdd(&deg[dst[e]], 1);
}

__global__ void k_scan_a(const int* __restrict__ deg, int* __restrict__ offs,
                         int* __restrict__ bsum) {
    __shared__ int sh[256];
    int tid  = threadIdx.x;
    int base = blockIdx.x * 1024 + tid * 4;
    int d0 = (base + 0 < N_NODES) ? deg[base + 0] : 0;
    int d1 = (base + 1 < N_NODES) ? deg[base + 1] : 0;
    int d2 = (base + 2 < N_NODES) ? deg[base + 2] : 0;
    int d3 = (base + 3 < N_NODES) ? deg[base + 3] : 0;
    int s = d0 + d1 + d2 + d3;
    sh[tid] = s;
    __syncthreads();
    for (int ofs = 1; ofs < 256; ofs <<= 1) {
        int v = (tid >= ofs) ? sh[tid - ofs] : 0;
        __syncthreads();
        sh[tid] += v;
        __syncthreads();
    }
    int excl = sh[tid] - s;
    if (base + 0 < N_NODES) offs[base + 0] = excl;
    if (base + 1 < N_NODES) offs[base + 1] = excl + d0;
    if (base + 2 < N_NODES) offs[base + 2] = excl + d0 + d1;
    if (base + 3 < N_NODES) offs[base + 3] = excl + d0 + d1 + d2;
    if (tid == 255) bsum[blockIdx.x] = sh[255];
}

__global__ void k_scan_b(const int* __restrict__ bsum, int* __restrict__ boff) {
    __shared__ int sh[128];
    int tid = threadIdx.x;                 // 128 threads, NB = 98
    int v = (tid < 98) ? bsum[tid] : 0;
    sh[tid] = v;
    __syncthreads();
    for (int ofs = 1; ofs < 128; ofs <<= 1) {
        int u = (tid >= ofs) ? sh[tid - ofs] : 0;
        __syncthreads();
        sh[tid] += u;
        __syncthreads();
    }
    if (tid < 98) boff[tid] = sh[tid] - v;
}

__global__ void k_scan_c(int* __restrict__ offs, const int* __restrict__ boff,
                         int* __restrict__ cur) {
    int tid  = threadIdx.x;
    int add  = boff[blockIdx.x];
    int base = blockIdx.x * 1024 + tid * 4;
    #pragma unroll
    for (int q = 0; q < 4; ++q) {
        int i = base + q;
        if (i < N_NODES) { int v = offs[i] + add; offs[i] = v; cur[i] = v; }
    }
}

__global__ void k_fill(const int* __restrict__ src, const int* __restrict__ dst,
                       const int* __restrict__ typ, int* __restrict__ cur,
                       int* __restrict__ csr) {
    int e = blockIdx.x * blockDim.x + threadIdx.x;
    if (e < N_EDGES) {
        int d = dst[e];
        int p = atomicAdd(&cur[d], 1);
        csr[p] = (src[e] << 3) | typ[e];    // (src*8 + t) -> 256B row of Htn
    }
}

// ---------------------------------------------------------------------------
// K4: m_agg[d][m] = sum over in-edges of Htn[(src*8+t)*64 + m]; wave/node.
// ---------------------------------------------------------------------------
__global__ void k_agg(const float* __restrict__ Htn, const int* __restrict__ offs,
                      const int* __restrict__ deg, const int* __restrict__ csr,
                      float* __restrict__ magg) {
    int gwave = (int)((blockIdx.x * blockDim.x + threadIdx.x) >> 6);
    int lane  = threadIdx.x & 63;
    int d = __builtin_amdgcn_readfirstlane(gwave);
    if (d >= N_NODES) return;
    int off = offs[d];
    int cnt = deg[d];
    float acc0 = 0.f, acc1 = 0.f, acc2 = 0.f, acc3 = 0.f;
    int k = 0;
    for (; k + 3 < cnt; k += 4) {
        int i0 = csr[off + k + 0];
        int i1 = csr[off + k + 1];
        int i2 = csr[off + k + 2];
        int i3 = csr[off + k + 3];
        acc0 += Htn[(size_t)i0 * 64 + lane];
        acc1 += Htn[(size_t)i1 * 64 + lane];
        acc2 += Htn[(size_t)i2 * 64 + lane];
        acc3 += Htn[(size_t)i3 * 64 + lane];
    }
    for (; k < cnt; ++k) acc0 += Htn[(size_t)csr[off + k] * 64 + lane];
    magg[(size_t)d * HID + lane] = (acc0 + acc1) + (acc2 + acc3);
}

// ---------------------------------------------------------------------------
// K5 v5: fused GRU as block-tiled GEMM. Block = 64 nodes, K=128 concat
// As = [magg | h] (transposed, 32KB). 4 gate-chunks share Bs[128][64]:
//  cc=0 r: K 0..127 (w_ih row j | w_hh row j)
//  cc=1 z: K 0..127 (rows 64+j)
//  cc=2 i_n: K 0..63  (w_ih rows 128+j)
//  cc=3 h_n: K 64..127 (w_hh rows 128+j)
// All 64 accs live; gate epilogue in registers; coalesced row stores.
// ---------------------------------------------------------------------------
#define GRU_FMA16(ACC)                                                        \
    ACC[0][0] = fmaf(av.x, bv.x, ACC[0][0]);                                  \
    ACC[0][1] = fmaf(av.x, bv.y, ACC[0][1]);                                  \
    ACC[0][2] = fmaf(av.x, bv.z, ACC[0][2]);                                  \
    ACC[0][3] = fmaf(av.x, bv.w, ACC[0][3]);                                  \
    ACC[1][0] = fmaf(av.y, bv.x, ACC[1][0]);                                  \
    ACC[1][1] = fmaf(av.y, bv.y, ACC[1][1]);                                  \
    ACC[1][2] = fmaf(av.y, bv.z, ACC[1][2]);                                  \
    ACC[1][3] = fmaf(av.y, bv.w, ACC[1][3]);                                  \
    ACC[2][0] = fmaf(av.z, bv.x, ACC[2][0]);                                  \
    ACC[2][1] = fmaf(av.z, bv.y, ACC[2][1]);                                  \
    ACC[2][2] = fmaf(av.z, bv.z, ACC[2][2]);                                  \
    ACC[2][3] = fmaf(av.z, bv.w, ACC[2][3]);                                  \
    ACC[3][0] = fmaf(av.w, bv.x, ACC[3][0]);                                  \
    ACC[3][1] = fmaf(av.w, bv.y, ACC[3][1]);                                  \
    ACC[3][2] = fmaf(av.w, bv.z, ACC[3][2]);                                  \
    ACC[3][3] = fmaf(av.w, bv.w, ACC[3][3]);

#define GRU_STAGE_B(WMAT, ROWBASE, KOFF)                                      \
    {                                                                         \
        const float4* w4 = (const float4*)(WMAT);                             \
        _Pragma("unroll")                                                     \
        for (int p = 0; p < 4; ++p) {                                         \
            int idx = p * 256 + tid;                                          \
            int j = idx & 63, q = idx >> 6;                                   \
            float4 v = w4[(size_t)((ROWBASE) + j) * 16 + q];                  \
            Bs[(KOFF) + q*4+0][j] = v.x; Bs[(KOFF) + q*4+1][j] = v.y;         \
            Bs[(KOFF) + q*4+2][j] = v.z; Bs[(KOFF) + q*4+3][j] = v.w;         \
        }                                                                     \
    }

#define GRU_COMPUTE(ACC, K0, K1)                                              \
    _Pragma("unroll")                                                         \
    for (int a = 0; a < 4; ++a)                                               \
        _Pragma("unroll")                                                     \
        for (int b = 0; b < 4; ++b) ACC[a][b] = 0.f;                          \
    _Pragma("unroll 16")                                                      \
    for (int k = (K0); k < (K1); ++k) {                                       \
        float4 av = *(const float4*)&As[k][i0];                               \
        float4 bv = *(const float4*)&Bs[k][j0];                               \
        GRU_FMA16(ACC)                                                        \
    }

__global__ __launch_bounds__(256) void k_gru(
        const float* __restrict__ h, const float* __restrict__ magg,
        const float* __restrict__ w_ih, const float* __restrict__ w_hh,
        const float* __restrict__ b_ih, const float* __restrict__ b_hh,
        float* __restrict__ out) {
    __shared__ float As[128][64];
    __shared__ float Bs[128][64];
    int tid = threadIdx.x;
    int n0  = blockIdx.x * 64;
    const float4* m4 = (const float4*)magg;
    const float4* h4 = (const float4*)h;

    // stage As: rows k=0..63 from magg, k=64..127 from h (transposed)
    #pragma unroll
    for (int p = 0; p < 4; ++p) {
        int idx = p * 256 + tid;
        int i = idx & 63, q = idx >> 6;
        int row = n0 + i; if (row >= N_NODES) row = N_NODES - 1;
        float4 vm = m4[(size_t)row * 16 + q];
        As[q*4+0][i] = vm.x; As[q*4+1][i] = vm.y;
        As[q*4+2][i] = vm.z; As[q*4+3][i] = vm.w;
        float4 vh = h4[(size_t)row * 16 + q];
        As[64 + q*4+0][i] = vh.x; As[64 + q*4+1][i] = vh.y;
        As[64 + q*4+2][i] = vh.z; As[64 + q*4+3][i] = vh.w;
    }

    int i0 = (tid >> 4) * 4;
    int j0 = (tid & 15) * 4;
    float accR[4][4], accZ[4][4], accIN[4][4], accHN[4][4];

    // r gate
    __syncthreads();
    GRU_STAGE_B(w_ih, 0, 0)
    GRU_STAGE_B(w_hh, 0, 64)
    __syncthreads();
    GRU_COMPUTE(accR, 0, 128)
    // z gate
    __syncthreads();
    GRU_STAGE_B(w_ih, 64, 0)
    GRU_STAGE_B(w_hh, 64, 64)
    __syncthreads();
    GRU_COMPUTE(accZ, 0, 128)
    // i_n
    __syncthreads();
    GRU_STAGE_B(w_ih, 128, 0)
    __syncthreads();
    GRU_COMPUTE(accIN, 0, 64)
    // h_n
    __syncthreads();
    GRU_STAGE_B(w_hh, 128, 64)
    __syncthreads();
    GRU_COMPUTE(accHN, 64, 128)

    // epilogue: biases + gates + blend, coalesced row stores
    float4 bir = *(const float4*)&b_ih[j0];
    float4 biz = *(const float4*)&b_ih[64 + j0];
    float4 bin = *(const float4*)&b_ih[128 + j0];
    float4 bhr = *(const float4*)&b_hh[j0];
    float4 bhz = *(const float4*)&b_hh[64 + j0];
    float4 bhn = *(const float4*)&b_hh[128 + j0];
    float br[4]  = {bir.x + bhr.x, bir.y + bhr.y, bir.z + bhr.z, bir.w + bhr.w};
    float bz[4]  = {biz.x + bhz.x, biz.y + bhz.y, biz.z + bhz.z, biz.w + bhz.w};
    float bn_i[4] = {bin.x, bin.y, bin.z, bin.w};
    float bn_h[4] = {bhn.x, bhn.y, bhn.z, bhn.w};

    #pragma unroll
    for (int ni = 0; ni < 4; ++ni) {
        int row = n0 + i0 + ni;
        if (row < N_NODES) {
            float4 hv = *(const float4*)&h[(size_t)row * HID + j0];
            float hvv[4] = {hv.x, hv.y, hv.z, hv.w};
            float o[4];
            #pragma unroll
            for (int jj = 0; jj < 4; ++jj) {
                float r  = 1.f / (1.f + __expf(-(accR[ni][jj] + br[jj])));
                float z  = 1.f / (1.f + __expf(-(accZ[ni][jj] + bz[jj])));
                float nn = tanhf(accIN[ni][jj] + bn_i[jj]
                                 + r * (accHN[ni][jj] + bn_h[jj]));
                o[jj] = (1.f - z) * nn + z * hvv[jj];
            }
            float4 o4; o4.x = o[0]; o4.y = o[1]; o4.z = o[2]; o4.w = o[3];
            *(float4*)&out[(size_t)row * HID + j0] = o4;
        }
    }
}

// ---------------------------------------------------------------------------
extern "C" void kernel_launch(void* const* d_in, const int* in_sizes, int n_in,
                              void* d_out, int out_size, void* d_ws, size_t ws_size,
                              hipStream_t stream) {
    const float* h    = (const float*)d_in[0];
    const float* em   = (const float*)d_in[1];
    const float* w_ih = (const float*)d_in[2];
    const float* w_hh = (const float*)d_in[3];
    const float* b_ih = (const float*)d_in[4];
    const float* b_hh = (const float*)d_in[5];
    const int* e_src  = (const int*)d_in[6];
    const int* e_dst  = (const int*)d_in[7];
    const int* e_typ  = (const int*)d_in[8];
    float* out = (float*)d_out;

    char* ws = (char*)d_ws;
    float* Htn  = (float*)(ws + WS_HT);
    float* magg = (float*)(ws + WS_MAGG);
    int* offs = (int*)(ws + WS_OFFS);
    int* deg  = (int*)(ws + WS_DEG);
    int* cur  = (int*)(ws + WS_CUR);
    int* csr  = (int*)(ws + WS_CSR);
    int* bsum = (int*)(ws + WS_BSUM);
    int* boff = (int*)(ws + WS_BOFF);

    hipMemsetAsync(deg, 0, (size_t)N_NODES * sizeof(int), stream);

    // Ht GEMM: 1563 node-tiles x 2 col-halves
    dim3 g1(1563, 2);
    k1_ht<<<g1, 256, 0, stream>>>(h, em, Htn);

    // CSR build
    k_hist<<<N_EDGES / 256, 256, 0, stream>>>(e_dst, deg);
    k_scan_a<<<98, 256, 0, stream>>>(deg, offs, bsum);
    k_scan_b<<<1, 128, 0, stream>>>(bsum, boff);
    k_scan_c<<<98, 256, 0, stream>>>(offs, boff, cur);
    k_fill<<<N_EDGES / 256, 256, 0, stream>>>(e_src, e_dst, e_typ, cur, csr);

    // aggregate: 100000 waves, 4 waves/block
    k_agg<<<25000, 256, 0, stream>>>(Htn, offs, deg, csr, magg);

    // fused GRU GEMM: 1563 node-tiles
    k_gru<<<1563, 256, 0, stream>>>(h, magg, w_ih, w_hh, b_ih, b_hh, out);
}

// Round 13
// 481.054 us; speedup vs baseline: 2.6377x; 1.0140x over previous
//
#include <hip/hip_runtime.h>

#define N_NODES 100000
#define N_EDGES 1280000
#define HID 64
#define N_ETYPE 8

// ---- workspace byte offsets (all 128B-aligned) ----
#define WS_HT    0ull            // Htn[n][512] f32 = 204,800,000 B
#define WS_MAGG  204800000ull    // N*64 f32   =  25,600,000 B
#define WS_OFFS  230400000ull    // N i32
#define WS_DEG   230800000ull    // N i32
#define WS_CUR   231200000ull    // N i32
#define WS_CSR   231600000ull    // E i32 = 5,120,000 B
#define WS_BSUM  236720000ull    // 128 i32
#define WS_BOFF  236720512ull    // 128 i32
// total ~236.8 MB

// ---------------------------------------------------------------------------
// K1 v6 (unchanged, measured <114us): block-tiled f32 GEMM.
// C[n][c] = sum_k h[n][k]*em[c*64+k]. Block = 64 nodes x 256 cols.
// ---------------------------------------------------------------------------
__global__ __launch_bounds__(256) void k1_ht(const float* __restrict__ h,
                                             const float* __restrict__ em,
                                             float* __restrict__ Htn) {
    __shared__ float As[64][64];
    __shared__ float Bs[64][64];
    int tid = threadIdx.x;
    int n0  = blockIdx.x * 64;
    const float4* h4  = (const float4*)h;
    const float4* em4 = (const float4*)em;

    #pragma unroll
    for (int p = 0; p < 4; ++p) {
        int idx = p * 256 + tid;
        int i = idx & 63, q = idx >> 6;          // q in 0..15
        int row = n0 + i; if (row >= N_NODES) row = N_NODES - 1;
        float4 v = h4[(size_t)row * 16 + q];
        As[q*4+0][i] = v.x; As[q*4+1][i] = v.y;
        As[q*4+2][i] = v.z; As[q*4+3][i] = v.w;
    }

    int i0 = (tid >> 4) * 4;     // node group
    int j0 = (tid & 15) * 4;     // col group

    #pragma unroll 1
    for (int cc = 0; cc < 4; ++cc) {
        int c0 = (blockIdx.y * 4 + cc) * 64;
        __syncthreads();   // previous compute done (and As ready on cc=0)
        #pragma unroll
        for (int p = 0; p < 4; ++p) {
            int idx = p * 256 + tid;
            int j = idx & 63, q = idx >> 6;
            float4 v = em4[(size_t)(c0 + j) * 16 + q];
            Bs[q*4+0][j] = v.x; Bs[q*4+1][j] = v.y;
            Bs[q*4+2][j] = v.z; Bs[q*4+3][j] = v.w;
        }
        __syncthreads();

        float acc[4][4];
        #pragma unroll
        for (int a = 0; a < 4; ++a)
            #pragma unroll
            for (int b = 0; b < 4; ++b) acc[a][b] = 0.f;

        #pragma unroll 16
        for (int k = 0; k < 64; ++k) {
            float4 av = *(const float4*)&As[k][i0];
            float4 bv = *(const float4*)&Bs[k][j0];
            acc[0][0] = fmaf(av.x, bv.x, acc[0][0]);
            acc[0][1] = fmaf(av.x, bv.y, acc[0][1]);
            acc[0][2] = fmaf(av.x, bv.z, acc[0][2]);
            acc[0][3] = fmaf(av.x, bv.w, acc[0][3]);
            acc[1][0] = fmaf(av.y, bv.x, acc[1][0]);
            acc[1][1] = fmaf(av.y, bv.y, acc[1][1]);
            acc[1][2] = fmaf(av.y, bv.z, acc[1][2]);
            acc[1][3] = fmaf(av.y, bv.w, acc[1][3]);
            acc[2][0] = fmaf(av.z, bv.x, acc[2][0]);
            acc[2][1] = fmaf(av.z, bv.y, acc[2][1]);
            acc[2][2] = fmaf(av.z, bv.z, acc[2][2]);
            acc[2][3] = fmaf(av.z, bv.w, acc[2][3]);
            acc[3][0] = fmaf(av.w, bv.x, acc[3][0]);
            acc[3][1] = fmaf(av.w, bv.y, acc[3][1]);
            acc[3][2] = fmaf(av.w, bv.z, acc[3][2]);
            acc[3][3] = fmaf(av.w, bv.w, acc[3][3]);
        }

        #pragma unroll
        for (int ni = 0; ni < 4; ++ni) {
            int row = n0 + i0 + ni;
            if (row < N_NODES) {
                float4 o; o.x = acc[ni][0]; o.y = acc[ni][1];
                o.z = acc[ni][2]; o.w = acc[ni][3];
                *(float4*)&Htn[(size_t)row * 512 + c0 + j0] = o;
            }
        }
    }
}

// ---------------------------------------------------------------------------
// CSR build: histogram -> 2-level exclusive scan -> fill
// ---------------------------------------------------------------------------
__global__ void k_hist(const int* __restrict__ dst, int* __restrict__ deg) {
    int e = blockIdx.x * blockDim.x + threadIdx.x;
    if (e < N_EDGES) atomicAdd(&deg[dst[e]], 1);
}

__global__ void k_scan_a(const int* __restrict__ deg, int* __restrict__ offs,
                         int* __restrict__ bsum) {
    __shared__ int sh[256];
    int tid  = threadIdx.x;
    int base = blockIdx.x * 1024 + tid * 4;
    int d0 = (base + 0 < N_NODES) ? deg[base + 0] : 0;
    int d1 = (base + 1 < N_NODES) ? deg[base + 1] : 0;
    int d2 = (base + 2 < N_NODES) ? deg[base + 2] : 0;
    int d3 = (base + 3 < N_NODES) ? deg[base + 3] : 0;
    int s = d0 + d1 + d2 + d3;
    sh[tid] = s;
    __syncthreads();
    for (int ofs = 1; ofs < 256; ofs <<= 1) {
        int v = (tid >= ofs) ? sh[tid - ofs] : 0;
        __syncthreads();
        sh[tid] += v;
        __syncthreads();
    }
    int excl = sh[tid] - s;
    if (base + 0 < N_NODES) offs[base + 0] = excl;
    if (base + 1 < N_NODES) offs[base + 1] = excl + d0;
    if (base + 2 < N_NODES) offs[base + 2] = excl + d0 + d1;
    if (base + 3 < N_NODES) offs[base + 3] = excl + d0 + d1 + d2;
    if (tid == 255) bsum[blockIdx.x] = sh[255];
}

__global__ void k_scan_b(const int* __restrict__ bsum, int* __restrict__ boff) {
    __shared__ int sh[128];
    int tid = threadIdx.x;                 // 128 threads, NB = 98
    int v = (tid < 98) ? bsum[tid] : 0;
    sh[tid] = v;
    __syncthreads();
    for (int ofs = 1; ofs < 128; ofs <<= 1) {
        int u = (tid >= ofs) ? sh[tid - ofs] : 0;
        __syncthreads();
        sh[tid] += u;
        __syncthreads();
    }
    if (tid < 98) boff[tid] = sh[tid] - v;
}

__global__ void k_scan_c(int* __restrict__ offs, const int* __restrict__ boff,
                         int* __restrict__ cur) {
    int tid  = threadIdx.x;
    int add  = boff[blockIdx.x];
    int base = blockIdx.x * 1024 + tid * 4;
    #pragma unroll
    for (int q = 0; q < 4; ++q) {
        int i = base + q;
        if (i < N_NODES) { int v = offs[i] + add; offs[i] = v; cur[i] = v; }
    }
}

__global__ void k_fill(const int* __restrict__ src, const int* __restrict__ dst,
                       const int* __restrict__ typ, int* __restrict__ cur,
                       int* __restrict__ csr) {
    int e = blockIdx.x * blockDim.x + threadIdx.x;
    if (e < N_EDGES) {
        int d = dst[e];
        int p = atomicAdd(&cur[d], 1);
        csr[p] = (src[e] << 3) | typ[e];    // (src*8 + t) -> 256B row of Htn
    }
}

// ---------------------------------------------------------------------------
// K4: m_agg[d][m] = sum over in-edges of Htn[(src*8+t)*64 + m]; wave/node.
// ---------------------------------------------------------------------------
__global__ void k_agg(const float* __restrict__ Htn, const int* __restrict__ offs,
                      const int* __restrict__ deg, const int* __restrict__ csr,
                      float* __restrict__ magg) {
    int gwave = (int)((blockIdx.x * blockDim.x + threadIdx.x) >> 6);
    int lane  = threadIdx.x & 63;
    int d = __builtin_amdgcn_readfirstlane(gwave);
    if (d >= N_NODES) return;
    int off = offs[d];
    int cnt = deg[d];
    float acc0 = 0.f, acc1 = 0.f, acc2 = 0.f, acc3 = 0.f;
    int k = 0;
    for (; k + 3 < cnt; k += 4) {
        int i0 = csr[off + k + 0];
        int i1 = csr[off + k + 1];
        int i2 = csr[off + k + 2];
        int i3 = csr[off + k + 3];
        acc0 += Htn[(size_t)i0 * 64 + lane];
        acc1 += Htn[(size_t)i1 * 64 + lane];
        acc2 += Htn[(size_t)i2 * 64 + lane];
        acc3 += Htn[(size_t)i3 * 64 + lane];
    }
    for (; k < cnt; ++k) acc0 += Htn[(size_t)csr[off + k] * 64 + lane];
    magg[(size_t)d * HID + lane] = (acc0 + acc1) + (acc2 + acc3);
}

// ---------------------------------------------------------------------------
// K5 v6: fused GRU GEMM, 6 phases of K=64 with 16KB Bs.
// LDS 48KB (As 32 + Bs 16) -> 3 blocks/CU (was 64KB -> 2 blocks/CU,
// Occupancy 17.7%, VALUBusy 45%). Accs persist across phases:
//  P1 accR += magg*w_ih[0:64)   P2 accR += h*w_hh[0:64)
//  P3 accZ += magg*w_ih[64:128) P4 accZ += h*w_hh[64:128)
//  P5 accIN += magg*w_ih[128:)  P6 accHN += h*w_hh[128:)
// ---------------------------------------------------------------------------
#define GRU_FMA16(ACC)                                                        \
    ACC[0][0] = fmaf(av.x, bv.x, ACC[0][0]);                                  \
    ACC[0][1] = fmaf(av.x, bv.y, ACC[0][1]);                                  \
    ACC[0][2] = fmaf(av.x, bv.z, ACC[0][2]);                                  \
    ACC[0][3] = fmaf(av.x, bv.w, ACC[0][3]);                                  \
    ACC[1][0] = fmaf(av.y, bv.x, ACC[1][0]);                                  \
    ACC[1][1] = fmaf(av.y, bv.y, ACC[1][1]);                                  \
    ACC[1][2] = fmaf(av.y, bv.z, ACC[1][2]);                                  \
    ACC[1][3] = fmaf(av.y, bv.w, ACC[1][3]);                                  \
    ACC[2][0] = fmaf(av.z, bv.x, ACC[2][0]);                                  \
    ACC[2][1] = fmaf(av.z, bv.y, ACC[2][1]);                                  \
    ACC[2][2] = fmaf(av.z, bv.z, ACC[2][2]);                                  \
    ACC[2][3] = fmaf(av.z, bv.w, ACC[2][3]);                                  \
    ACC[3][0] = fmaf(av.w, bv.x, ACC[3][0]);                                  \
    ACC[3][1] = fmaf(av.w, bv.y, ACC[3][1]);                                  \
    ACC[3][2] = fmaf(av.w, bv.z, ACC[3][2]);                                  \
    ACC[3][3] = fmaf(av.w, bv.w, ACC[3][3]);

// stage Bs[k][j] = W[(ROWBASE+j)*64 + k]  (transposed, coalesced float4)
#define GRU_STAGE_B6(WMAT, ROWBASE)                                           \
    {                                                                         \
        const float4* w4 = (const float4*)(WMAT);                             \
        _Pragma("unroll")                                                     \
        for (int p = 0; p < 4; ++p) {                                         \
            int idx = p * 256 + tid;                                          \
            int j = idx & 63, q = idx >> 6;                                   \
            float4 v = w4[(size_t)((ROWBASE) + j) * 16 + q];                  \
            Bs[q*4+0][j] = v.x; Bs[q*4+1][j] = v.y;                           \
            Bs[q*4+2][j] = v.z; Bs[q*4+3][j] = v.w;                           \
        }                                                                     \
    }

// ACC += As[KBASE..KBASE+63][i0..] * Bs[0..63][j0..]
#define GRU_COMPUTE_ADD(ACC, KBASE)                                           \
    _Pragma("unroll 16")                                                      \
    for (int k = 0; k < 64; ++k) {                                            \
        float4 av = *(const float4*)&As[(KBASE) + k][i0];                     \
        float4 bv = *(const float4*)&Bs[k][j0];                               \
        GRU_FMA16(ACC)                                                        \
    }

__global__ __launch_bounds__(256, 3) void k_gru(
        const float* __restrict__ h, const float* __restrict__ magg,
        const float* __restrict__ w_ih, const float* __restrict__ w_hh,
        const float* __restrict__ b_ih, const float* __restrict__ b_hh,
        float* __restrict__ out) {
    __shared__ float As[128][64];   // 32KB: k=0..63 magg^T, 64..127 h^T
    __shared__ float Bs[64][64];    // 16KB
    int tid = threadIdx.x;
    int n0  = blockIdx.x * 64;
    const float4* m4 = (const float4*)magg;
    const float4* h4 = (const float4*)h;

    // stage As (transposed), and first Bs, before ONE barrier
    #pragma unroll
    for (int p = 0; p < 4; ++p) {
        int idx = p * 256 + tid;
        int i = idx & 63, q = idx >> 6;
        int row = n0 + i; if (row >= N_NODES) row = N_NODES - 1;
        float4 vm = m4[(size_t)row * 16 + q];
        As[q*4+0][i] = vm.x; As[q*4+1][i] = vm.y;
        As[q*4+2][i] = vm.z; As[q*4+3][i] = vm.w;
        float4 vh = h4[(size_t)row * 16 + q];
        As[64 + q*4+0][i] = vh.x; As[64 + q*4+1][i] = vh.y;
        As[64 + q*4+2][i] = vh.z; As[64 + q*4+3][i] = vh.w;
    }
    GRU_STAGE_B6(w_ih, 0)

    int i0 = (tid >> 4) * 4;
    int j0 = (tid & 15) * 4;
    float accR[4][4], accZ[4][4], accIN[4][4], accHN[4][4];
    #pragma unroll
    for (int a = 0; a < 4; ++a)
        #pragma unroll
        for (int b = 0; b < 4; ++b) {
            accR[a][b] = 0.f; accZ[a][b] = 0.f;
            accIN[a][b] = 0.f; accHN[a][b] = 0.f;
        }

    __syncthreads();
    GRU_COMPUTE_ADD(accR, 0)          // P1: magg * w_ih_r
    __syncthreads();
    GRU_STAGE_B6(w_hh, 0)
    __syncthreads();
    GRU_COMPUTE_ADD(accR, 64)         // P2: h * w_hh_r
    __syncthreads();
    GRU_STAGE_B6(w_ih, 64)
    __syncthreads();
    GRU_COMPUTE_ADD(accZ, 0)          // P3: magg * w_ih_z
    __syncthreads();
    GRU_STAGE_B6(w_hh, 64)
    __syncthreads();
    GRU_COMPUTE_ADD(accZ, 64)         // P4: h * w_hh_z
    __syncthreads();
    GRU_STAGE_B6(w_ih, 128)
    __syncthreads();
    GRU_COMPUTE_ADD(accIN, 0)         // P5: magg * w_ih_n
    __syncthreads();
    GRU_STAGE_B6(w_hh, 128)
    __syncthreads();
    GRU_COMPUTE_ADD(accHN, 64)        // P6: h * w_hh_n

    // epilogue: biases + gates + blend, coalesced row stores
    float4 bir = *(const float4*)&b_ih[j0];
    float4 biz = *(const float4*)&b_ih[64 + j0];
    float4 bin = *(const float4*)&b_ih[128 + j0];
    float4 bhr = *(const float4*)&b_hh[j0];
    float4 bhz = *(const float4*)&b_hh[64 + j0];
    float4 bhn = *(const float4*)&b_hh[128 + j0];
    float br[4]  = {bir.x + bhr.x, bir.y + bhr.y, bir.z + bhr.z, bir.w + bhr.w};
    float bz[4]  = {biz.x + bhz.x, biz.y + bhz.y, biz.z + bhz.z, biz.w + bhz.w};
    float bn_i[4] = {bin.x, bin.y, bin.z, bin.w};
    float bn_h[4] = {bhn.x, bhn.y, bhn.z, bhn.w};

    #pragma unroll
    for (int ni = 0; ni < 4; ++ni) {
        int row = n0 + i0 + ni;
        if (row < N_NODES) {
            float4 hv = *(const float4*)&h[(size_t)row * HID + j0];
            float hvv[4] = {hv.x, hv.y, hv.z, hv.w};
            float o[4];
            #pragma unroll
            for (int jj = 0; jj < 4; ++jj) {
                float r  = 1.f / (1.f + __expf(-(accR[ni][jj] + br[jj])));
                float z  = 1.f / (1.f + __expf(-(accZ[ni][jj] + bz[jj])));
                float nn = tanhf(accIN[ni][jj] + bn_i[jj]
                                 + r * (accHN[ni][jj] + bn_h[jj]));
                o[jj] = (1.f - z) * nn + z * hvv[jj];
            }
            float4 o4; o4.x = o[0]; o4.y = o[1]; o4.z = o[2]; o4.w = o[3];
            *(float4*)&out[(size_t)row * HID + j0] = o4;
        }
    }
}

// ---------------------------------------------------------------------------
extern "C" void kernel_launch(void* const* d_in, const int* in_sizes, int n_in,
                              void* d_out, int out_size, void* d_ws, size_t ws_size,
                              hipStream_t stream) {
    const float* h    = (const float*)d_in[0];
    const float* em   = (const float*)d_in[1];
    const float* w_ih = (const float*)d_in[2];
    const float* w_hh = (const float*)d_in[3];
    const float* b_ih = (const float*)d_in[4];
    const float* b_hh = (const float*)d_in[5];
    const int* e_src  = (const int*)d_in[6];
    const int* e_dst  = (const int*)d_in[7];
    const int* e_typ  = (const int*)d_in[8];
    float* out = (float*)d_out;

    char* ws = (char*)d_ws;
    float* Htn  = (float*)(ws + WS_HT);
    float* magg = (float*)(ws + WS_MAGG);
    int* offs = (int*)(ws + WS_OFFS);
    int* deg  = (int*)(ws + WS_DEG);
    int* cur  = (int*)(ws + WS_CUR);
    int* csr  = (int*)(ws + WS_CSR);
    int* bsum = (int*)(ws + WS_BSUM);
    int* boff = (int*)(ws + WS_BOFF);

    hipMemsetAsync(deg, 0, (size_t)N_NODES * sizeof(int), stream);

    // Ht GEMM: 1563 node-tiles x 2 col-halves
    dim3 g1(1563, 2);
    k1_ht<<<g1, 256, 0, stream>>>(h, em, Htn);

    // CSR build
    k_hist<<<N_EDGES / 256, 256, 0, stream>>>(e_dst, deg);
    k_scan_a<<<98, 256, 0, stream>>>(deg, offs, bsum);
    k_scan_b<<<1, 128, 0, stream>>>(bsum, boff);
    k_scan_c<<<98, 256, 0, stream>>>(offs, boff, cur);
    k_fill<<<N_EDGES / 256, 256, 0, stream>>>(e_src, e_dst, e_typ, cur, csr);

    // aggregate: 100000 waves, 4 waves/block
    k_agg<<<25000, 256, 0, stream>>>(Htn, offs, deg, csr, magg);

    // fused GRU GEMM: 1563 node-tiles, 6-phase
    k_gru<<<1563, 256, 0, stream>>>(h, magg, w_ih, w_hh, b_ih, b_hh, out);
}